// Round 4
// baseline (8344.896 us; speedup 1.0000x reference)
//
#include <hip/hip_runtime.h>
#include <hip/hip_bf16.h>

// GRU encoder: B=64, T=100, E=512, U=512.
// d_out = FLOAT32: output [B,T,U] then states [2,B,U]  (3,342,336 floats).
// ws requirement ~131 MB (xs 13.1M + preactA 39.3M + preactB 39.3M + ycat 26.2M
//                         + packed hi/lo weights 12.6M + h/rh tiles + barriers).

#define TT 100

using f32x4 = __attribute__((ext_vector_type(4))) float;
using s16x8 = __attribute__((ext_vector_type(8))) short;

__device__ __forceinline__ unsigned short f2bfu(float x) {
  __hip_bfloat16 b = __float2bfloat16(x);
  unsigned short u;
  __builtin_memcpy(&u, &b, sizeof(u));
  return u;
}
__device__ __forceinline__ float bfu2f(unsigned short u) {
  __hip_bfloat16 b;
  __builtin_memcpy(&b, &u, sizeof(b));
  return __bfloat162float(b);
}
__device__ __forceinline__ float sigm(float x) {
  x = fminf(fmaxf(x, -30.f), 30.f);
  return 1.f / (1.f + __expf(-x));
}
__device__ __forceinline__ float tanh_fast(float x) {
  x = fminf(fmaxf(x, -15.f), 15.f);
  float e = __expf(-2.f * x);
  return (1.f - e) / (1.f + e);
}

// ---------------------------------------------------------------- embedding
__global__ __launch_bounds__(128) void embed_kernel(const int* __restrict__ x,
                                                    const float* __restrict__ emb,
                                                    float* __restrict__ xs) {
  const int row = blockIdx.x;            // row = t*64 + b  (time-major)
  const int t = row >> 6, b = row & 63;
  const int idx = x[b * TT + t];
  const f32x4* s = (const f32x4*)(emb + (size_t)idx * 512);
  f32x4* d = (f32x4*)(xs + (size_t)row * 512);
  d[threadIdx.x] = s[threadIdx.x];       // 128 thr * 16B = 2KB row
}

// ------------------------------------------------- pack recurrent weights
// B-fragment layout for mfma_f32_16x16x32_bf16, split into bf16 hi/lo.
// Layout: [nt 0..95][kt 0..15][lane 0..63][elem 0..7]; nt 0..63 = gate cols
// (0..1023), nt 64..95 = candidate cols (0..511). k = h-part rows (ein + k).
__global__ __launch_bounds__(256) void pack_w_kernel(const float* __restrict__ Wg,
                                                     const float* __restrict__ Wc,
                                                     int ldg, int ldc, int ein,
                                                     unsigned short* __restrict__ hi,
                                                     unsigned short* __restrict__ lo) {
  const int gg = blockIdx.x * 256 + threadIdx.x;
  if (gg >= 96 * 16 * 64) return;
  const int lane = gg & 63;
  const int pair = gg >> 6;
  const int kt = pair & 15;
  const int nt = pair >> 4;
  const int kg = lane >> 4;
  const int nl = lane & 15;
  const size_t off = (size_t)gg * 8;
  for (int i = 0; i < 8; ++i) {
    const int k = kt * 32 + kg * 8 + i;
    float v = (nt < 64) ? Wg[(size_t)(ein + k) * ldg + nt * 16 + nl]
                        : Wc[(size_t)(ein + k) * ldc + (nt - 64) * 16 + nl];
    unsigned short h = f2bfu(v);
    hi[off + i] = h;
    lo[off + i] = f2bfu(v - bfu2f(h));
  }
}

// ------------------------------------------------------- fp32 input-proj GEMM
// C[seg] = A[M,K] @ W[K,Nseg] + bias, 128x128 tiles, 8x8 micro/thread.
struct GemmSegs {
  int seg_end[4];          // exclusive n boundaries, ascending
  const float* w[4];
  int ldw[4];
  const float* bias[4];
  float* c[4];
  int col0[4];             // column offset into dest (ldc = 1536)
};

__global__ __launch_bounds__(256) void gemm_f32_kernel(const float* __restrict__ A,
                                                       int lda, int K, GemmSegs segs) {
  __shared__ float As[16][132];   // [k][m], padded
  __shared__ float Bs[16][132];   // [k][n], padded
  const int tid = threadIdx.x;
  const int bm = blockIdx.x, bn = blockIdx.y;
  const int n0 = bn * 128;
  int s = 0;
  while (n0 >= segs.seg_end[s]) ++s;
  const int segst = s ? segs.seg_end[s - 1] : 0;
  const float* W = segs.w[s];
  const int ldw = segs.ldw[s];
  const float* bias = segs.bias[s] + (n0 - segst);
  float* C = segs.c[s];
  const int ccol = segs.col0[s] + (n0 - segst);
  const int wn0 = n0 - segst;

  const int alr = tid >> 1, alc = (tid & 1) * 8;   // A tile load: 128 rows x 16 k
  const int blr = tid >> 4, blc = (tid & 15) * 8;  // B tile load: 16 k x 128 n
  const int tm = tid >> 4, tn = tid & 15;

  float acc[8][8] = {};
  const float* Arow = A + (size_t)(bm * 128 + alr) * lda + alc;
  const float* Wrow = W + (size_t)blr * ldw + wn0 + blc;

  for (int k0 = 0; k0 < K; k0 += 16) {
    f32x4 a0 = *(const f32x4*)(Arow + k0);
    f32x4 a1 = *(const f32x4*)(Arow + k0 + 4);
    f32x4 b0 = *(const f32x4*)(Wrow + (size_t)k0 * ldw);
    f32x4 b1 = *(const f32x4*)(Wrow + (size_t)k0 * ldw + 4);
#pragma unroll
    for (int i = 0; i < 4; ++i) {
      As[alc + i][alr] = a0[i];
      As[alc + 4 + i][alr] = a1[i];
    }
    *(f32x4*)&Bs[blr][blc] = b0;
    *(f32x4*)&Bs[blr][blc + 4] = b1;
    __syncthreads();
#pragma unroll
    for (int kk = 0; kk < 16; ++kk) {
      f32x4 xa = *(const f32x4*)&As[kk][tm * 4];
      f32x4 xb = *(const f32x4*)&As[kk][64 + tm * 4];
      f32x4 ya = *(const f32x4*)&Bs[kk][tn * 4];
      f32x4 yb = *(const f32x4*)&Bs[kk][64 + tn * 4];
#pragma unroll
      for (int i = 0; i < 4; ++i)
#pragma unroll
        for (int j = 0; j < 4; ++j) {
          acc[i][j] += xa[i] * ya[j];
          acc[i][j + 4] += xa[i] * yb[j];
          acc[i + 4][j] += xb[i] * ya[j];
          acc[i + 4][j + 4] += xb[i] * yb[j];
        }
    }
    __syncthreads();
  }
  float bv[8];
#pragma unroll
  for (int j = 0; j < 4; ++j) {
    bv[j] = bias[tn * 4 + j];
    bv[j + 4] = bias[64 + tn * 4 + j];
  }
#pragma unroll
  for (int i = 0; i < 8; ++i) {
    const int row = bm * 128 + ((i < 4) ? (tm * 4 + i) : (64 + tm * 4 + i - 4));
    float* cp = C + (size_t)row * 1536 + ccol;
    f32x4 v0, v1;
#pragma unroll
    for (int j = 0; j < 4; ++j) {
      v0[j] = acc[i][j] + bv[j];
      v1[j] = acc[i][j + 4] + bv[j + 4];
    }
    *(f32x4*)(cp + tn * 4) = v0;
    *(f32x4*)(cp + 64 + tn * 4) = v1;
  }
}

// ------------------------------------------------------------ group barrier
// Agent-scope sense-reversing barrier; RMW-poll so it is correct regardless of
// workgroup->XCD placement (no reliance on L2 snooping).
__device__ __forceinline__ void group_barrier(int* cnt, int* gen, int members) {
  __syncthreads();
  if (threadIdx.x == 0) {
    int g0 = __hip_atomic_load(gen, __ATOMIC_RELAXED, __HIP_MEMORY_SCOPE_AGENT);
    int prev = __hip_atomic_fetch_add(cnt, 1, __ATOMIC_ACQ_REL, __HIP_MEMORY_SCOPE_AGENT);
    if (prev == members - 1) {
      __hip_atomic_store(cnt, 0, __ATOMIC_RELAXED, __HIP_MEMORY_SCOPE_AGENT);
      __hip_atomic_fetch_add(gen, 1, __ATOMIC_ACQ_REL, __HIP_MEMORY_SCOPE_AGENT);
    } else {
      while (__hip_atomic_fetch_add(gen, 0, __ATOMIC_ACQUIRE, __HIP_MEMORY_SCOPE_AGENT) == g0) {
        __builtin_amdgcn_s_sleep(8);
      }
    }
  }
  __syncthreads();
}

// ------------------------------------------------------------- GRU scan
// Grid 256 WGs = 8 groups x 32 WGs. Group g = bid&7, WG owns hidden slice
// [wg*16, wg*16+16). NB = batches per group (16 bidir / 8 uni). Recurrent
// weights live in LDS as hi/lo bf16 B-fragments; per step:
//   phase1: gates = h @ Wg_h + Gx (3x MFMA split-bf16), r,u = sigmoid
//   -> write r*h (hi/lo, swizzled) to global, group barrier
//   phase2: cand = (r*h) @ Wc_h + Cx, h' = u*h + (1-u)*tanh(cand)
//   -> write h' (hi/lo) + y, group barrier.
template <int NB>
__global__ __launch_bounds__(256, 1) void gru_scan_kernel(
    const float* __restrict__ gxF, const float* __restrict__ gxB,
    const unsigned short* __restrict__ wHiF, const unsigned short* __restrict__ wLoF,
    const unsigned short* __restrict__ wHiB, const unsigned short* __restrict__ wLoB,
    unsigned short* __restrict__ hHiG, unsigned short* __restrict__ hLoG,
    unsigned short* __restrict__ rHiG, unsigned short* __restrict__ rLoG,
    int* __restrict__ bars,
    float* __restrict__ yout, int yld,
    float* __restrict__ outb,
    float* __restrict__ stout) {
  __shared__ unsigned short wHi_s[3 * 8192];   // 48KB: [r|u|c] tiles
  __shared__ unsigned short wLo_s[3 * 8192];   // 48KB
  __shared__ unsigned short hHi_s[8192];       // 16KB: [16][512] swizzled (h, then rh)
  __shared__ unsigned short hLo_s[8192];       // 16KB
  __shared__ float scr[4][16][17];             // per-wave MFMA partials [wv][b][c]
  __shared__ float u_s[16][16];
  __shared__ float hown[16][16];

  const int tid = threadIdx.x;
  const int lane = tid & 63;
  const int wv = tid >> 6;
  const int bid = blockIdx.x;
  const int g = bid & 7;
  const int wg = bid >> 3;        // 0..31
  const int hs = wg << 4;

  int dir = 0, b0;
  const float* gx;
  const unsigned short *wph, *wpl;
  if (NB == 16) {
    dir = g & 1;
    b0 = (g >> 1) << 4;
    gx = dir ? gxB : gxF;
    wph = dir ? wHiB : wHiF;
    wpl = dir ? wLoB : wLoF;
  } else {
    b0 = g * NB;
    gx = gxF;
    wph = wHiF;
    wpl = wLoF;
  }

  // load stationary weight fragments to LDS
  {
    const int nt0[3] = {wg, 32 + wg, 64 + wg};
    for (int c = 0; c < 3; ++c) {
      const unsigned short* sH = wph + (size_t)nt0[c] * 8192;
      const unsigned short* sL = wpl + (size_t)nt0[c] * 8192;
      unsigned short* dH = wHi_s + c * 8192;
      unsigned short* dL = wLo_s + c * 8192;
#pragma unroll
      for (int it = 0; it < 4; ++it) {
        const int o = (it * 256 + tid) * 8;
        *(s16x8*)(dH + o) = *(const s16x8*)(sH + o);
        *(s16x8*)(dL + o) = *(const s16x8*)(sL + o);
      }
    }
  }
  // h(t=0) = 0
  {
    s16x8 z = {0, 0, 0, 0, 0, 0, 0, 0};
#pragma unroll
    for (int it = 0; it < 4; ++it) {
      const int o = (it * 256 + tid) * 8;
      *(s16x8*)(hHi_s + o) = z;
      *(s16x8*)(hLo_s + o) = z;
    }
  }
  __syncthreads();

  int* bcnt = bars + g * 64;
  int* bgen = bars + g * 64 + 32;

  // MFMA lane constants: A row = lane&15, k-group = lane>>4 (8 elems)
  const int fm = lane & 15;
  const int fkg = lane >> 4;
  const int arow = fm * 512;
  const int asw = (fm & 7) << 3;   // XOR swizzle (ushort units) to spread banks
  const int akof = fkg * 8;

  const int oc = tid & 31, ob = tid >> 5;   // phase-1 owners: (b, gate-col)
  const int p2j = tid & 15, p2b = tid >> 4; // phase-2 owners: (b, cand-col)

  const size_t tileo = (size_t)g * 8192;

  for (int t = 0; t < TT; ++t) {
    const int tg = dir ? (TT - 1 - t) : t;
    const float* gxrow = gx + ((size_t)tg * 64 + b0) * 1536;
    // prefetch this step's preactivation values (x-projections incl bias)
    const int gcol = (oc < 16) ? (hs + oc) : (512 + hs + (oc - 16));
    const float gxa = gxrow[ob * 1536 + gcol];
    const float gxb_ = (NB == 16) ? gxrow[(ob + 8) * 1536 + gcol] : 0.f;
    const float gxc = (p2b < NB) ? gxrow[p2b * 1536 + 1024 + hs + p2j] : 0.f;

    if (t > 0) {  // stage h tile (hi/lo, already swizzled in global)
#pragma unroll
      for (int it = 0; it < NB / 4; ++it) {
        const int o = (it * 256 + tid) * 8;
        *(s16x8*)(hHi_s + o) = *(const s16x8*)(hHiG + tileo + o);
        *(s16x8*)(hLo_s + o) = *(const s16x8*)(hLoG + tileo + o);
      }
    }
    __syncthreads();

    // ---- phase 1: gate preacts = h @ Wg_h ----
    {
      f32x4 acc0 = {0.f, 0.f, 0.f, 0.f}, acc1 = {0.f, 0.f, 0.f, 0.f};
      const int ntl = wv & 1;            // 0 = r tile, 1 = u tile
      const int ktb = (wv >> 1) * 8;     // k-half
#pragma unroll
      for (int q = 0; q < 8; ++q) {
        const int kt = ktb + q;
        const int ao = arow + ((kt * 32 + akof) ^ asw);
        s16x8 ah = *(const s16x8*)(hHi_s + ao);
        s16x8 al = *(const s16x8*)(hLo_s + ao);
        const int wo = ((ntl * 16 + kt) * 64 + lane) * 8;
        s16x8 bh = *(const s16x8*)(wHi_s + wo);
        s16x8 bl = *(const s16x8*)(wLo_s + wo);
        if (q & 1) {
          acc1 = __builtin_amdgcn_mfma_f32_16x16x32_bf16(ah, bh, acc1, 0, 0, 0);
          acc1 = __builtin_amdgcn_mfma_f32_16x16x32_bf16(ah, bl, acc1, 0, 0, 0);
          acc1 = __builtin_amdgcn_mfma_f32_16x16x32_bf16(al, bh, acc1, 0, 0, 0);
        } else {
          acc0 = __builtin_amdgcn_mfma_f32_16x16x32_bf16(ah, bh, acc0, 0, 0, 0);
          acc0 = __builtin_amdgcn_mfma_f32_16x16x32_bf16(ah, bl, acc0, 0, 0, 0);
          acc0 = __builtin_amdgcn_mfma_f32_16x16x32_bf16(al, bh, acc0, 0, 0, 0);
        }
      }
#pragma unroll
      for (int j = 0; j < 4; ++j) scr[wv][fkg * 4 + j][fm] = acc0[j] + acc1[j];
    }
    __syncthreads();
    // phase-1 owners: sigmoid, write r*h (hi/lo) to global, keep u and h
#pragma unroll
    for (int rep = 0; rep < (NB == 16 ? 2 : 1); ++rep) {
      const int b = ob + rep * 8;
      const int ntl = (oc < 16) ? 0 : 1;
      const int cc = oc & 15;
      float pre = scr[ntl][b][cc] + scr[ntl + 2][b][cc] + (rep ? gxb_ : gxa);
      float sg = sigm(pre);
      if (oc < 16) {
        const int ui = b * 512 + ((hs + cc) ^ ((b & 7) << 3));
        float hv = bfu2f(hHi_s[ui]) + bfu2f(hLo_s[ui]);
        hown[b][cc] = hv;
        float rh = sg * hv;
        unsigned short rhh = f2bfu(rh);
        rHiG[tileo + ui] = rhh;
        rLoG[tileo + ui] = f2bfu(rh - bfu2f(rhh));
      } else {
        u_s[b][cc] = sg;
      }
    }
    group_barrier(bcnt, bgen, 32);
    // stage full r*h tile (overwrites h in LDS; h kept in hown)
#pragma unroll
    for (int it = 0; it < NB / 4; ++it) {
      const int o = (it * 256 + tid) * 8;
      *(s16x8*)(hHi_s + o) = *(const s16x8*)(rHiG + tileo + o);
      *(s16x8*)(hLo_s + o) = *(const s16x8*)(rLoG + tileo + o);
    }
    __syncthreads();

    // ---- phase 2: cand preacts = (r*h) @ Wc_h ----
    {
      f32x4 acc0 = {0.f, 0.f, 0.f, 0.f}, acc1 = {0.f, 0.f, 0.f, 0.f};
      const int ktb = wv * 4;            // k-quarter
#pragma unroll
      for (int q = 0; q < 4; ++q) {
        const int kt = ktb + q;
        const int ao = arow + ((kt * 32 + akof) ^ asw);
        s16x8 ah = *(const s16x8*)(hHi_s + ao);
        s16x8 al = *(const s16x8*)(hLo_s + ao);
        const int wo = ((32 + kt) * 64 + lane) * 8;
        s16x8 bh = *(const s16x8*)(wHi_s + wo);
        s16x8 bl = *(const s16x8*)(wLo_s + wo);
        if (q & 1) {
          acc1 = __builtin_amdgcn_mfma_f32_16x16x32_bf16(ah, bh, acc1, 0, 0, 0);
          acc1 = __builtin_amdgcn_mfma_f32_16x16x32_bf16(ah, bl, acc1, 0, 0, 0);
          acc1 = __builtin_amdgcn_mfma_f32_16x16x32_bf16(al, bh, acc1, 0, 0, 0);
        } else {
          acc0 = __builtin_amdgcn_mfma_f32_16x16x32_bf16(ah, bh, acc0, 0, 0, 0);
          acc0 = __builtin_amdgcn_mfma_f32_16x16x32_bf16(ah, bl, acc0, 0, 0, 0);
          acc0 = __builtin_amdgcn_mfma_f32_16x16x32_bf16(al, bh, acc0, 0, 0, 0);
        }
      }
#pragma unroll
      for (int j = 0; j < 4; ++j) scr[wv][fkg * 4 + j][fm] = acc0[j] + acc1[j];
    }
    __syncthreads();
    // phase-2 owners: tanh, h update, outputs
    if (p2b < NB) {
      float pre = scr[0][p2b][p2j] + scr[1][p2b][p2j] + scr[2][p2b][p2j] +
                  scr[3][p2b][p2j] + gxc;
      float cv = tanh_fast(pre);
      float uv = u_s[p2b][p2j];
      float hn = uv * hown[p2b][p2j] + (1.f - uv) * cv;
      const int ui = p2b * 512 + ((hs + p2j) ^ ((p2b & 7) << 3));
      unsigned short hh = f2bfu(hn);
      hHiG[tileo + ui] = hh;
      hLoG[tileo + ui] = f2bfu(hn - bfu2f(hh));
      if (yout) {
        const int ycol = (NB == 16) ? (dir * 512 + hs + p2j) : (hs + p2j);
        yout[((size_t)tg * 64 + (b0 + p2b)) * yld + ycol] = hn;
      }
      if (outb)
        outb[((size_t)(b0 + p2b) * TT + t) * 512 + hs + p2j] = hn;
      if (stout && t == TT - 1)
        stout[(size_t)(b0 + p2b) * 512 + hs + p2j] = hn;
    }
    group_barrier(bcnt, bgen, 32);
  }
}

// ---------------------------------------------------------------- launcher
extern "C" void kernel_launch(void* const* d_in, const int* in_sizes, int n_in,
                              void* d_out, int out_size, void* d_ws, size_t ws_size,
                              hipStream_t stream) {
  (void)in_sizes; (void)n_in; (void)out_size; (void)ws_size;
  const int* x = (const int*)d_in[0];
  const float* emb = (const float*)d_in[1];
  const float* WgFw = (const float*)d_in[2];
  const float* bgFw = (const float*)d_in[3];
  const float* WcFw = (const float*)d_in[4];
  const float* bcFw = (const float*)d_in[5];
  const float* WgBw = (const float*)d_in[6];
  const float* bgBw = (const float*)d_in[7];
  const float* WcBw = (const float*)d_in[8];
  const float* bcBw = (const float*)d_in[9];
  const float* WgU1 = (const float*)d_in[10];
  const float* bgU1 = (const float*)d_in[11];
  const float* WcU1 = (const float*)d_in[12];
  const float* bcU1 = (const float*)d_in[13];
  const float* WgU2 = (const float*)d_in[14];
  const float* bgU2 = (const float*)d_in[15];
  const float* WcU2 = (const float*)d_in[16];
  const float* bcU2 = (const float*)d_in[17];

  char* ws = (char*)d_ws;
  float* xs = (float*)(ws + 0);                      // 13,107,200 B
  float* bufA = (float*)(ws + 13107200);             // 39,321,600 B (fw preacts / u1 preacts)
  float* bufB = (float*)(ws + 52428800);             // 39,321,600 B (bw preacts / u2 preacts)
  float* ycat = (float*)(ws + 91750400);             // 26,214,400 B
  unsigned short* wp = (unsigned short*)(ws + 117964800);  // 12,582,912 B packed
  unsigned short* hb = (unsigned short*)(ws + 130547712);  // 524,288 B h/rh tiles
  int* bars = (int*)(ws + 131072000);                // 4 KB
  float* y1 = xs;        // reuse (xs dead after bidir GEMM)
  float* gxU1 = bufA;    // reuse (bufA dead after bidir scan)
  float* gxU2 = bufB;

  unsigned short* wpFwHi = wp + 0 * 786432;
  unsigned short* wpFwLo = wp + 1 * 786432;
  unsigned short* wpBwHi = wp + 2 * 786432;
  unsigned short* wpBwLo = wp + 3 * 786432;
  unsigned short* wpU1Hi = wp + 4 * 786432;
  unsigned short* wpU1Lo = wp + 5 * 786432;
  unsigned short* wpU2Hi = wp + 6 * 786432;
  unsigned short* wpU2Lo = wp + 7 * 786432;
  unsigned short* hHiG = hb;
  unsigned short* hLoG = hb + 65536;
  unsigned short* rHiG = hb + 131072;
  unsigned short* rLoG = hb + 196608;

  float* out = (float*)d_out;
  float* st1 = out + (size_t)64 * TT * 512;
  float* st2 = st1 + 64 * 512;

  hipMemsetAsync(bars, 0, 4096, stream);

  embed_kernel<<<6400, 128, 0, stream>>>(x, emb, xs);
  pack_w_kernel<<<384, 256, 0, stream>>>(WgFw, WcFw, 1024, 512, 512, wpFwHi, wpFwLo);
  pack_w_kernel<<<384, 256, 0, stream>>>(WgBw, WcBw, 1024, 512, 512, wpBwHi, wpBwLo);
  pack_w_kernel<<<384, 256, 0, stream>>>(WgU1, WcU1, 1024, 512, 1024, wpU1Hi, wpU1Lo);
  pack_w_kernel<<<384, 256, 0, stream>>>(WgU2, WcU2, 1024, 512, 512, wpU2Hi, wpU2Lo);

  {  // bidirectional input projections: [6400,512] x [512,3072]
    GemmSegs sg;
    sg.seg_end[0] = 1024; sg.seg_end[1] = 1536; sg.seg_end[2] = 2560; sg.seg_end[3] = 3072;
    sg.w[0] = WgFw; sg.w[1] = WcFw; sg.w[2] = WgBw; sg.w[3] = WcBw;
    sg.ldw[0] = 1024; sg.ldw[1] = 512; sg.ldw[2] = 1024; sg.ldw[3] = 512;
    sg.bias[0] = bgFw; sg.bias[1] = bcFw; sg.bias[2] = bgBw; sg.bias[3] = bcBw;
    sg.c[0] = bufA; sg.c[1] = bufA; sg.c[2] = bufB; sg.c[3] = bufB;
    sg.col0[0] = 0; sg.col0[1] = 1024; sg.col0[2] = 0; sg.col0[3] = 1024;
    gemm_f32_kernel<<<dim3(50, 24), 256, 0, stream>>>(xs, 512, 512, sg);
  }
  {  // bidirectional scan (fw + bw concurrently)
    const float *a0 = bufA, *a1 = bufB;
    const unsigned short *w0 = wpFwHi, *w1 = wpFwLo, *w2 = wpBwHi, *w3 = wpBwLo;
    unsigned short *h0 = hHiG, *h1 = hLoG, *r0 = rHiG, *r1 = rLoG;
    int* bp = bars;
    float* yo = ycat; int yld = 1024;
    float *on = nullptr, *sn = nullptr;
    void* args[] = {&a0, &a1, &w0, &w1, &w2, &w3, &h0, &h1, &r0, &r1,
                    &bp, &yo, &yld, &on, &sn};
    hipLaunchCooperativeKernel((const void*)gru_scan_kernel<16>, dim3(256), dim3(256),
                               args, 0, stream);
  }
  {  // u1 input projections: [6400,1024] x [1024,1536]
    GemmSegs sg;
    sg.seg_end[0] = 1024; sg.seg_end[1] = 1536; sg.seg_end[2] = 1 << 30; sg.seg_end[3] = 1 << 30;
    sg.w[0] = WgU1; sg.w[1] = WcU1; sg.w[2] = nullptr; sg.w[3] = nullptr;
    sg.ldw[0] = 1024; sg.ldw[1] = 512; sg.ldw[2] = 0; sg.ldw[3] = 0;
    sg.bias[0] = bgU1; sg.bias[1] = bcU1; sg.bias[2] = nullptr; sg.bias[3] = nullptr;
    sg.c[0] = gxU1; sg.c[1] = gxU1; sg.c[2] = nullptr; sg.c[3] = nullptr;
    sg.col0[0] = 0; sg.col0[1] = 1024; sg.col0[2] = 0; sg.col0[3] = 0;
    gemm_f32_kernel<<<dim3(50, 12), 256, 0, stream>>>(ycat, 1024, 1024, sg);
  }
  {  // u1 scan
    const float *a0 = gxU1, *a1 = nullptr;
    const unsigned short *w0 = wpU1Hi, *w1 = wpU1Lo, *w2 = nullptr, *w3 = nullptr;
    unsigned short *h0 = hHiG, *h1 = hLoG, *r0 = rHiG, *r1 = rLoG;
    int* bp = bars;
    float* yo = y1; int yld = 512;
    float *on = nullptr, *sn = st1;
    void* args[] = {&a0, &a1, &w0, &w1, &w2, &w3, &h0, &h1, &r0, &r1,
                    &bp, &yo, &yld, &on, &sn};
    hipLaunchCooperativeKernel((const void*)gru_scan_kernel<8>, dim3(256), dim3(256),
                               args, 0, stream);
  }
  {  // u2 input projections: [6400,512] x [512,1536]
    GemmSegs sg;
    sg.seg_end[0] = 1024; sg.seg_end[1] = 1536; sg.seg_end[2] = 1 << 30; sg.seg_end[3] = 1 << 30;
    sg.w[0] = WgU2; sg.w[1] = WcU2; sg.w[2] = nullptr; sg.w[3] = nullptr;
    sg.ldw[0] = 1024; sg.ldw[1] = 512; sg.ldw[2] = 0; sg.ldw[3] = 0;
    sg.bias[0] = bgU2; sg.bias[1] = bcU2; sg.bias[2] = nullptr; sg.bias[3] = nullptr;
    sg.c[0] = gxU2; sg.c[1] = gxU2; sg.c[2] = nullptr; sg.c[3] = nullptr;
    sg.col0[0] = 0; sg.col0[1] = 1024; sg.col0[2] = 0; sg.col0[3] = 0;
    gemm_f32_kernel<<<dim3(50, 12), 256, 0, stream>>>(y1, 512, 512, sg);
  }
  {  // u2 scan -> d_out (f32) + state2
    const float *a0 = gxU2, *a1 = nullptr;
    const unsigned short *w0 = wpU2Hi, *w1 = wpU2Lo, *w2 = nullptr, *w3 = nullptr;
    unsigned short *h0 = hHiG, *h1 = hLoG, *r0 = rHiG, *r1 = rLoG;
    int* bp = bars;
    float* yo = nullptr; int yld = 0;
    float *on = out, *sn = st2;
    void* args[] = {&a0, &a1, &w0, &w1, &w2, &w3, &h0, &h1, &r0, &r1,
                    &bp, &yo, &yld, &on, &sn};
    hipLaunchCooperativeKernel((const void*)gru_scan_kernel<8>, dim3(256), dim3(256),
                               args, 0, stream);
  }
}

// Round 5
// 2226.907 us; speedup vs baseline: 3.7473x; 3.7473x over previous
//
#include <hip/hip_runtime.h>
#include <hip/hip_bf16.h>

// GRU encoder: B=64, T=100, E=512, U=512.
// d_out = FLOAT32: output [B,T,U] then states [2,B,U]  (3,342,336 floats).
// Scan sync rework: sc0/sc1 (LLC-coherent) data path + monotonic slot barrier.
// ws requirement ~131 MB.

#define TT 100

using f32x4 = __attribute__((ext_vector_type(4))) float;
using s16x8 = __attribute__((ext_vector_type(8))) short;

__device__ __forceinline__ unsigned short f2bfu(float x) {
  __hip_bfloat16 b = __float2bfloat16(x);
  unsigned short u;
  __builtin_memcpy(&u, &b, sizeof(u));
  return u;
}
__device__ __forceinline__ float bfu2f(unsigned short u) {
  __hip_bfloat16 b;
  __builtin_memcpy(&b, &u, sizeof(b));
  return __bfloat162float(b);
}
__device__ __forceinline__ float sigm(float x) {
  x = fminf(fmaxf(x, -30.f), 30.f);
  return 1.f / (1.f + __expf(-x));
}
__device__ __forceinline__ float tanh_fast(float x) {
  x = fminf(fmaxf(x, -15.f), 15.f);
  float e = __expf(-2.f * x);
  return (1.f - e) / (1.f + e);
}

// ---- LLC-coherent (bypass L1/L2) access helpers: no buffer_inv/wbl2 needed ----
__device__ __forceinline__ s16x8 sc1_load_b128(const void* p) {
  s16x8 v;
  asm volatile("global_load_dwordx4 %0, %1, off sc0 sc1" : "=v"(v) : "v"(p) : "memory");
  return v;
}
__device__ __forceinline__ void sc1_store_b16(void* p, unsigned v) {
  asm volatile("global_store_short %0, %1, off sc0 sc1" :: "v"(p), "v"(v) : "memory");
}
__device__ __forceinline__ void vm_drain() {
  asm volatile("s_waitcnt vmcnt(0)" ::: "memory");
}

// ------------------------------------------------------------ group barrier
// Monotonic slot barrier: after per-wave vmcnt drain + __syncthreads, tid0
// publishes `target` to its slot (sc1 store -> LLC); wave 0 polls all 32
// slots (one sc1 dword per lane) until all >= target. No RMW contention,
// no cache-wide maintenance ops.
__device__ __forceinline__ void wg_arrive_wait(unsigned* slots, int wg, unsigned target) {
  vm_drain();
  __syncthreads();
  if (threadIdx.x == 0) {
    unsigned* p = slots + wg;
    asm volatile("global_store_dword %0, %1, off sc0 sc1" :: "v"(p), "v"(target) : "memory");
  }
  if (threadIdx.x < 32) {
    const unsigned* p = slots + threadIdx.x;
    unsigned v;
    do {
      asm volatile("global_load_dword %0, %1, off sc0 sc1\n\ts_waitcnt vmcnt(0)"
                   : "=v"(v) : "v"(p) : "memory");
    } while (!__all(v >= target));
  }
  __syncthreads();
}

// ---------------------------------------------------------------- embedding
__global__ __launch_bounds__(128) void embed_kernel(const int* __restrict__ x,
                                                    const float* __restrict__ emb,
                                                    float* __restrict__ xs) {
  const int row = blockIdx.x;            // row = t*64 + b  (time-major)
  const int t = row >> 6, b = row & 63;
  const int idx = x[b * TT + t];
  const f32x4* s = (const f32x4*)(emb + (size_t)idx * 512);
  f32x4* d = (f32x4*)(xs + (size_t)row * 512);
  d[threadIdx.x] = s[threadIdx.x];       // 128 thr * 16B = 2KB row
}

// ------------------------------------------------- pack recurrent weights
// B-fragment layout for mfma_f32_16x16x32_bf16, split into bf16 hi/lo.
// Layout: [nt 0..95][kt 0..15][lane 0..63][elem 0..7]; nt 0..63 = gate cols
// (0..1023), nt 64..95 = candidate cols (0..511). k = h-part rows (ein + k).
__global__ __launch_bounds__(256) void pack_w_kernel(const float* __restrict__ Wg,
                                                     const float* __restrict__ Wc,
                                                     int ldg, int ldc, int ein,
                                                     unsigned short* __restrict__ hi,
                                                     unsigned short* __restrict__ lo) {
  const int gg = blockIdx.x * 256 + threadIdx.x;
  if (gg >= 96 * 16 * 64) return;
  const int lane = gg & 63;
  const int pair = gg >> 6;
  const int kt = pair & 15;
  const int nt = pair >> 4;
  const int kg = lane >> 4;
  const int nl = lane & 15;
  const size_t off = (size_t)gg * 8;
  for (int i = 0; i < 8; ++i) {
    const int k = kt * 32 + kg * 8 + i;
    float v = (nt < 64) ? Wg[(size_t)(ein + k) * ldg + nt * 16 + nl]
                        : Wc[(size_t)(ein + k) * ldc + (nt - 64) * 16 + nl];
    unsigned short h = f2bfu(v);
    hi[off + i] = h;
    lo[off + i] = f2bfu(v - bfu2f(h));
  }
}

// ------------------------------------------------------- fp32 input-proj GEMM
// C[seg] = A[M,K] @ W[K,Nseg] + bias, 128x128 tiles, 8x8 micro/thread.
struct GemmSegs {
  int seg_end[4];          // exclusive n boundaries, ascending
  const float* w[4];
  int ldw[4];
  const float* bias[4];
  float* c[4];
  int col0[4];             // column offset into dest (ldc = 1536)
};

__global__ __launch_bounds__(256) void gemm_f32_kernel(const float* __restrict__ A,
                                                       int lda, int K, GemmSegs segs) {
  __shared__ float As[16][132];   // [k][m], padded
  __shared__ float Bs[16][132];   // [k][n], padded
  const int tid = threadIdx.x;
  const int bm = blockIdx.x, bn = blockIdx.y;
  const int n0 = bn * 128;
  int s = 0;
  while (n0 >= segs.seg_end[s]) ++s;
  const int segst = s ? segs.seg_end[s - 1] : 0;
  const float* W = segs.w[s];
  const int ldw = segs.ldw[s];
  const float* bias = segs.bias[s] + (n0 - segst);
  float* C = segs.c[s];
  const int ccol = segs.col0[s] + (n0 - segst);
  const int wn0 = n0 - segst;

  const int alr = tid >> 1, alc = (tid & 1) * 8;   // A tile load: 128 rows x 16 k
  const int blr = tid >> 4, blc = (tid & 15) * 8;  // B tile load: 16 k x 128 n
  const int tm = tid >> 4, tn = tid & 15;

  float acc[8][8] = {};
  const float* Arow = A + (size_t)(bm * 128 + alr) * lda + alc;
  const float* Wrow = W + (size_t)blr * ldw + wn0 + blc;

  for (int k0 = 0; k0 < K; k0 += 16) {
    f32x4 a0 = *(const f32x4*)(Arow + k0);
    f32x4 a1 = *(const f32x4*)(Arow + k0 + 4);
    f32x4 b0 = *(const f32x4*)(Wrow + (size_t)k0 * ldw);
    f32x4 b1 = *(const f32x4*)(Wrow + (size_t)k0 * ldw + 4);
#pragma unroll
    for (int i = 0; i < 4; ++i) {
      As[alc + i][alr] = a0[i];
      As[alc + 4 + i][alr] = a1[i];
    }
    *(f32x4*)&Bs[blr][blc] = b0;
    *(f32x4*)&Bs[blr][blc + 4] = b1;
    __syncthreads();
#pragma unroll
    for (int kk = 0; kk < 16; ++kk) {
      f32x4 xa = *(const f32x4*)&As[kk][tm * 4];
      f32x4 xb = *(const f32x4*)&As[kk][64 + tm * 4];
      f32x4 ya = *(const f32x4*)&Bs[kk][tn * 4];
      f32x4 yb = *(const f32x4*)&Bs[kk][64 + tn * 4];
#pragma unroll
      for (int i = 0; i < 4; ++i)
#pragma unroll
        for (int j = 0; j < 4; ++j) {
          acc[i][j] += xa[i] * ya[j];
          acc[i][j + 4] += xa[i] * yb[j];
          acc[i + 4][j] += xb[i] * ya[j];
          acc[i + 4][j + 4] += xb[i] * yb[j];
        }
    }
    __syncthreads();
  }
  float bv[8];
#pragma unroll
  for (int j = 0; j < 4; ++j) {
    bv[j] = bias[tn * 4 + j];
    bv[j + 4] = bias[64 + tn * 4 + j];
  }
#pragma unroll
  for (int i = 0; i < 8; ++i) {
    const int row = bm * 128 + ((i < 4) ? (tm * 4 + i) : (64 + tm * 4 + i - 4));
    float* cp = C + (size_t)row * 1536 + ccol;
    f32x4 v0, v1;
#pragma unroll
    for (int j = 0; j < 4; ++j) {
      v0[j] = acc[i][j] + bv[j];
      v1[j] = acc[i][j + 4] + bv[j + 4];
    }
    *(f32x4*)(cp + tn * 4) = v0;
    *(f32x4*)(cp + 64 + tn * 4) = v1;
  }
}

// ------------------------------------------------------------- GRU scan
// Grid 256 WGs = 8 groups x 32 WGs. Group g = bid&7, WG owns hidden slice
// [wg*16, wg*16+16). NB = batches per group (16 bidir / 8 uni). Recurrent
// weights live in LDS as hi/lo bf16 B-fragments; per step:
//   phase1: gates = h @ Wg_h + Gx (3x MFMA split-bf16), r,u = sigmoid
//   -> sc1-write r*h (hi/lo, swizzled), slot barrier
//   phase2: cand = (r*h) @ Wc_h + Cx, h' = u*h + (1-u)*tanh(cand)
//   -> sc1-write h' (hi/lo) + y, slot barrier (skipped on last step).
template <int NB>
__global__ __launch_bounds__(256, 1) void gru_scan_kernel(
    const float* __restrict__ gxF, const float* __restrict__ gxB,
    const unsigned short* __restrict__ wHiF, const unsigned short* __restrict__ wLoF,
    const unsigned short* __restrict__ wHiB, const unsigned short* __restrict__ wLoB,
    unsigned short* __restrict__ hHiG, unsigned short* __restrict__ hLoG,
    unsigned short* __restrict__ rHiG, unsigned short* __restrict__ rLoG,
    unsigned* __restrict__ slots,
    float* __restrict__ yout, int yld,
    float* __restrict__ outb,
    float* __restrict__ stout) {
  __shared__ unsigned short wHi_s[3 * 8192];   // 48KB: [r|u|c] tiles
  __shared__ unsigned short wLo_s[3 * 8192];   // 48KB
  __shared__ unsigned short hHi_s[8192];       // 16KB: [16][512] swizzled (h, then rh)
  __shared__ unsigned short hLo_s[8192];       // 16KB
  __shared__ float scr[4][16][17];             // per-wave MFMA partials [wv][b][c]
  __shared__ float u_s[16][16];
  __shared__ float hown[16][16];

  const int tid = threadIdx.x;
  const int lane = tid & 63;
  const int wv = tid >> 6;
  const int bid = blockIdx.x;
  const int g = bid & 7;
  const int wg = bid >> 3;        // 0..31
  const int hs = wg << 4;

  int dir = 0, b0;
  const float* gx;
  const unsigned short *wph, *wpl;
  if (NB == 16) {
    dir = g & 1;
    b0 = (g >> 1) << 4;
    gx = dir ? gxB : gxF;
    wph = dir ? wHiB : wHiF;
    wpl = dir ? wLoB : wLoF;
  } else {
    b0 = g * NB;
    gx = gxF;
    wph = wHiF;
    wpl = wLoF;
  }

  // load stationary weight fragments to LDS
  {
    const int nt0[3] = {wg, 32 + wg, 64 + wg};
    for (int c = 0; c < 3; ++c) {
      const unsigned short* sH = wph + (size_t)nt0[c] * 8192;
      const unsigned short* sL = wpl + (size_t)nt0[c] * 8192;
      unsigned short* dH = wHi_s + c * 8192;
      unsigned short* dL = wLo_s + c * 8192;
#pragma unroll
      for (int it = 0; it < 4; ++it) {
        const int o = (it * 256 + tid) * 8;
        *(s16x8*)(dH + o) = *(const s16x8*)(sH + o);
        *(s16x8*)(dL + o) = *(const s16x8*)(sL + o);
      }
    }
  }
  // h(t=0) = 0
  {
    s16x8 z = {0, 0, 0, 0, 0, 0, 0, 0};
#pragma unroll
    for (int it = 0; it < 4; ++it) {
      const int o = (it * 256 + tid) * 8;
      *(s16x8*)(hHi_s + o) = z;
      *(s16x8*)(hLo_s + o) = z;
    }
  }
  __syncthreads();

  unsigned* gslots = slots + g * 32;

  // MFMA lane constants: A row = lane&15, k-group = lane>>4 (8 elems)
  const int fm = lane & 15;
  const int fkg = lane >> 4;
  const int arow = fm * 512;
  const int asw = (fm & 7) << 3;   // XOR swizzle (ushort units) to spread banks
  const int akof = fkg * 8;

  const int oc = tid & 31, ob = tid >> 5;   // phase-1 owners: (b, gate-col)
  const int p2j = tid & 15, p2b = tid >> 4; // phase-2 owners: (b, cand-col)

  const size_t tileo = (size_t)g * 8192;

  for (int t = 0; t < TT; ++t) {
    const int tg = dir ? (TT - 1 - t) : t;
    const float* gxrow = gx + ((size_t)tg * 64 + b0) * 1536;
    // prefetch this step's preactivation values (x-projections incl bias)
    const int gcol = (oc < 16) ? (hs + oc) : (512 + hs + (oc - 16));
    const float gxa = gxrow[ob * 1536 + gcol];
    const float gxb_ = (NB == 16) ? gxrow[(ob + 8) * 1536 + gcol] : 0.f;
    const float gxc = (p2b < NB) ? gxrow[p2b * 1536 + 1024 + hs + p2j] : 0.f;

    if (t > 0) {  // stage h tile from LLC (sc1; already swizzled in global)
      s16x8 th[4], tl[4];
#pragma unroll
      for (int it = 0; it < NB / 4; ++it) {
        const int o = (it * 256 + tid) * 8;
        th[it] = sc1_load_b128(hHiG + tileo + o);
        tl[it] = sc1_load_b128(hLoG + tileo + o);
      }
      vm_drain();
#pragma unroll
      for (int it = 0; it < NB / 4; ++it) {
        const int o = (it * 256 + tid) * 8;
        *(s16x8*)(hHi_s + o) = th[it];
        *(s16x8*)(hLo_s + o) = tl[it];
      }
    }
    __syncthreads();

    // ---- phase 1: gate preacts = h @ Wg_h ----
    {
      f32x4 acc0 = {0.f, 0.f, 0.f, 0.f}, acc1 = {0.f, 0.f, 0.f, 0.f};
      const int ntl = wv & 1;            // 0 = r tile, 1 = u tile
      const int ktb = (wv >> 1) * 8;     // k-half
#pragma unroll
      for (int q = 0; q < 8; ++q) {
        const int kt = ktb + q;
        const int ao = arow + ((kt * 32 + akof) ^ asw);
        s16x8 ah = *(const s16x8*)(hHi_s + ao);
        s16x8 al = *(const s16x8*)(hLo_s + ao);
        const int wo = ((ntl * 16 + kt) * 64 + lane) * 8;
        s16x8 bh = *(const s16x8*)(wHi_s + wo);
        s16x8 bl = *(const s16x8*)(wLo_s + wo);
        if (q & 1) {
          acc1 = __builtin_amdgcn_mfma_f32_16x16x32_bf16(ah, bh, acc1, 0, 0, 0);
          acc1 = __builtin_amdgcn_mfma_f32_16x16x32_bf16(ah, bl, acc1, 0, 0, 0);
          acc1 = __builtin_amdgcn_mfma_f32_16x16x32_bf16(al, bh, acc1, 0, 0, 0);
        } else {
          acc0 = __builtin_amdgcn_mfma_f32_16x16x32_bf16(ah, bh, acc0, 0, 0, 0);
          acc0 = __builtin_amdgcn_mfma_f32_16x16x32_bf16(ah, bl, acc0, 0, 0, 0);
          acc0 = __builtin_amdgcn_mfma_f32_16x16x32_bf16(al, bh, acc0, 0, 0, 0);
        }
      }
#pragma unroll
      for (int j = 0; j < 4; ++j) scr[wv][fkg * 4 + j][fm] = acc0[j] + acc1[j];
    }
    __syncthreads();
    // phase-1 owners: sigmoid, sc1-write r*h (hi/lo), keep u and h
#pragma unroll
    for (int rep = 0; rep < (NB == 16 ? 2 : 1); ++rep) {
      const int b = ob + rep * 8;
      const int ntl = (oc < 16) ? 0 : 1;
      const int cc = oc & 15;
      float pre = scr[ntl][b][cc] + scr[ntl + 2][b][cc] + (rep ? gxb_ : gxa);
      float sg = sigm(pre);
      if (oc < 16) {
        const int ui = b * 512 + ((hs + cc) ^ ((b & 7) << 3));
        float hv = bfu2f(hHi_s[ui]) + bfu2f(hLo_s[ui]);
        hown[b][cc] = hv;
        float rh = sg * hv;
        unsigned short rhh = f2bfu(rh);
        sc1_store_b16(rHiG + tileo + ui, rhh);
        sc1_store_b16(rLoG + tileo + ui, f2bfu(rh - bfu2f(rhh)));
      } else {
        u_s[b][cc] = sg;
      }
    }
    wg_arrive_wait(gslots, wg, 2 * t + 1);
    // stage full r*h tile (overwrites h in LDS; h kept in hown)
    {
      s16x8 th[4], tl[4];
#pragma unroll
      for (int it = 0; it < NB / 4; ++it) {
        const int o = (it * 256 + tid) * 8;
        th[it] = sc1_load_b128(rHiG + tileo + o);
        tl[it] = sc1_load_b128(rLoG + tileo + o);
      }
      vm_drain();
#pragma unroll
      for (int it = 0; it < NB / 4; ++it) {
        const int o = (it * 256 + tid) * 8;
        *(s16x8*)(hHi_s + o) = th[it];
        *(s16x8*)(hLo_s + o) = tl[it];
      }
    }
    __syncthreads();

    // ---- phase 2: cand preacts = (r*h) @ Wc_h ----
    {
      f32x4 acc0 = {0.f, 0.f, 0.f, 0.f}, acc1 = {0.f, 0.f, 0.f, 0.f};
      const int ktb = wv * 4;            // k-quarter
#pragma unroll
      for (int q = 0; q < 4; ++q) {
        const int kt = ktb + q;
        const int ao = arow + ((kt * 32 + akof) ^ asw);
        s16x8 ah = *(const s16x8*)(hHi_s + ao);
        s16x8 al = *(const s16x8*)(hLo_s + ao);
        const int wo = ((32 + kt) * 64 + lane) * 8;
        s16x8 bh = *(const s16x8*)(wHi_s + wo);
        s16x8 bl = *(const s16x8*)(wLo_s + wo);
        if (q & 1) {
          acc1 = __builtin_amdgcn_mfma_f32_16x16x32_bf16(ah, bh, acc1, 0, 0, 0);
          acc1 = __builtin_amdgcn_mfma_f32_16x16x32_bf16(ah, bl, acc1, 0, 0, 0);
          acc1 = __builtin_amdgcn_mfma_f32_16x16x32_bf16(al, bh, acc1, 0, 0, 0);
        } else {
          acc0 = __builtin_amdgcn_mfma_f32_16x16x32_bf16(ah, bh, acc0, 0, 0, 0);
          acc0 = __builtin_amdgcn_mfma_f32_16x16x32_bf16(ah, bl, acc0, 0, 0, 0);
          acc0 = __builtin_amdgcn_mfma_f32_16x16x32_bf16(al, bh, acc0, 0, 0, 0);
        }
      }
#pragma unroll
      for (int j = 0; j < 4; ++j) scr[wv][fkg * 4 + j][fm] = acc0[j] + acc1[j];
    }
    __syncthreads();
    // phase-2 owners: tanh, h update, outputs
    if (p2b < NB) {
      float pre = scr[0][p2b][p2j] + scr[1][p2b][p2j] + scr[2][p2b][p2j] +
                  scr[3][p2b][p2j] + gxc;
      float cv = tanh_fast(pre);
      float uv = u_s[p2b][p2j];
      float hn = uv * hown[p2b][p2j] + (1.f - uv) * cv;
      const int ui = p2b * 512 + ((hs + p2j) ^ ((p2b & 7) << 3));
      unsigned short hh = f2bfu(hn);
      sc1_store_b16(hHiG + tileo + ui, hh);
      sc1_store_b16(hLoG + tileo + ui, f2bfu(hn - bfu2f(hh)));
      if (yout) {
        const int ycol = (NB == 16) ? (dir * 512 + hs + p2j) : (hs + p2j);
        yout[((size_t)tg * 64 + (b0 + p2b)) * yld + ycol] = hn;
      }
      if (outb)
        outb[((size_t)(b0 + p2b) * TT + t) * 512 + hs + p2j] = hn;
      if (stout && t == TT - 1)
        stout[(size_t)(b0 + p2b) * 512 + hs + p2j] = hn;
    }
    if (t != TT - 1) wg_arrive_wait(gslots, wg, 2 * t + 2);
  }
}

// ---------------------------------------------------------------- launcher
extern "C" void kernel_launch(void* const* d_in, const int* in_sizes, int n_in,
                              void* d_out, int out_size, void* d_ws, size_t ws_size,
                              hipStream_t stream) {
  (void)in_sizes; (void)n_in; (void)out_size; (void)ws_size;
  const int* x = (const int*)d_in[0];
  const float* emb = (const float*)d_in[1];
  const float* WgFw = (const float*)d_in[2];
  const float* bgFw = (const float*)d_in[3];
  const float* WcFw = (const float*)d_in[4];
  const float* bcFw = (const float*)d_in[5];
  const float* WgBw = (const float*)d_in[6];
  const float* bgBw = (const float*)d_in[7];
  const float* WcBw = (const float*)d_in[8];
  const float* bcBw = (const float*)d_in[9];
  const float* WgU1 = (const float*)d_in[10];
  const float* bgU1 = (const float*)d_in[11];
  const float* WcU1 = (const float*)d_in[12];
  const float* bcU1 = (const float*)d_in[13];
  const float* WgU2 = (const float*)d_in[14];
  const float* bgU2 = (const float*)d_in[15];
  const float* WcU2 = (const float*)d_in[16];
  const float* bcU2 = (const float*)d_in[17];

  char* ws = (char*)d_ws;
  float* xs = (float*)(ws + 0);                      // 13,107,200 B
  float* bufA = (float*)(ws + 13107200);             // 39,321,600 B (fw preacts / u1 preacts)
  float* bufB = (float*)(ws + 52428800);             // 39,321,600 B (bw preacts / u2 preacts)
  float* ycat = (float*)(ws + 91750400);             // 26,214,400 B
  unsigned short* wp = (unsigned short*)(ws + 117964800);  // 12,582,912 B packed
  unsigned short* hb = (unsigned short*)(ws + 130547712);  // 524,288 B h/rh tiles
  unsigned* bars = (unsigned*)(ws + 131072000);      // 3 x 256 u32 slot arrays
  float* y1 = xs;        // reuse (xs dead after bidir GEMM)
  float* gxU1 = bufA;    // reuse (bufA dead after bidir scan)
  float* gxU2 = bufB;

  unsigned short* wpFwHi = wp + 0 * 786432;
  unsigned short* wpFwLo = wp + 1 * 786432;
  unsigned short* wpBwHi = wp + 2 * 786432;
  unsigned short* wpBwLo = wp + 3 * 786432;
  unsigned short* wpU1Hi = wp + 4 * 786432;
  unsigned short* wpU1Lo = wp + 5 * 786432;
  unsigned short* wpU2Hi = wp + 6 * 786432;
  unsigned short* wpU2Lo = wp + 7 * 786432;
  unsigned short* hHiG = hb;
  unsigned short* hLoG = hb + 65536;
  unsigned short* rHiG = hb + 131072;
  unsigned short* rLoG = hb + 196608;

  float* out = (float*)d_out;
  float* st1 = out + (size_t)64 * TT * 512;
  float* st2 = st1 + 64 * 512;

  hipMemsetAsync(bars, 0, 4096, stream);

  embed_kernel<<<6400, 128, 0, stream>>>(x, emb, xs);
  pack_w_kernel<<<384, 256, 0, stream>>>(WgFw, WcFw, 1024, 512, 512, wpFwHi, wpFwLo);
  pack_w_kernel<<<384, 256, 0, stream>>>(WgBw, WcBw, 1024, 512, 512, wpBwHi, wpBwLo);
  pack_w_kernel<<<384, 256, 0, stream>>>(WgU1, WcU1, 1024, 512, 1024, wpU1Hi, wpU1Lo);
  pack_w_kernel<<<384, 256, 0, stream>>>(WgU2, WcU2, 1024, 512, 512, wpU2Hi, wpU2Lo);

  {  // bidirectional input projections: [6400,512] x [512,3072]
    GemmSegs sg;
    sg.seg_end[0] = 1024; sg.seg_end[1] = 1536; sg.seg_end[2] = 2560; sg.seg_end[3] = 3072;
    sg.w[0] = WgFw; sg.w[1] = WcFw; sg.w[2] = WgBw; sg.w[3] = WcBw;
    sg.ldw[0] = 1024; sg.ldw[1] = 512; sg.ldw[2] = 1024; sg.ldw[3] = 512;
    sg.bias[0] = bgFw; sg.bias[1] = bcFw; sg.bias[2] = bgBw; sg.bias[3] = bcBw;
    sg.c[0] = bufA; sg.c[1] = bufA; sg.c[2] = bufB; sg.c[3] = bufB;
    sg.col0[0] = 0; sg.col0[1] = 1024; sg.col0[2] = 0; sg.col0[3] = 1024;
    gemm_f32_kernel<<<dim3(50, 24), 256, 0, stream>>>(xs, 512, 512, sg);
  }
  {  // bidirectional scan (fw + bw concurrently)
    const float *a0 = bufA, *a1 = bufB;
    const unsigned short *w0 = wpFwHi, *w1 = wpFwLo, *w2 = wpBwHi, *w3 = wpBwLo;
    unsigned short *h0 = hHiG, *h1 = hLoG, *r0 = rHiG, *r1 = rLoG;
    unsigned* bp = bars;
    float* yo = ycat; int yld = 1024;
    float *on = nullptr, *sn = nullptr;
    void* args[] = {&a0, &a1, &w0, &w1, &w2, &w3, &h0, &h1, &r0, &r1,
                    &bp, &yo, &yld, &on, &sn};
    hipLaunchCooperativeKernel((const void*)gru_scan_kernel<16>, dim3(256), dim3(256),
                               args, 0, stream);
  }
  {  // u1 input projections: [6400,1024] x [1024,1536]
    GemmSegs sg;
    sg.seg_end[0] = 1024; sg.seg_end[1] = 1536; sg.seg_end[2] = 1 << 30; sg.seg_end[3] = 1 << 30;
    sg.w[0] = WgU1; sg.w[1] = WcU1; sg.w[2] = nullptr; sg.w[3] = nullptr;
    sg.ldw[0] = 1024; sg.ldw[1] = 512; sg.ldw[2] = 0; sg.ldw[3] = 0;
    sg.bias[0] = bgU1; sg.bias[1] = bcU1; sg.bias[2] = nullptr; sg.bias[3] = nullptr;
    sg.c[0] = gxU1; sg.c[1] = gxU1; sg.c[2] = nullptr; sg.c[3] = nullptr;
    sg.col0[0] = 0; sg.col0[1] = 1024; sg.col0[2] = 0; sg.col0[3] = 0;
    gemm_f32_kernel<<<dim3(50, 12), 256, 0, stream>>>(ycat, 1024, 1024, sg);
  }
  {  // u1 scan
    const float *a0 = gxU1, *a1 = nullptr;
    const unsigned short *w0 = wpU1Hi, *w1 = wpU1Lo, *w2 = nullptr, *w3 = nullptr;
    unsigned short *h0 = hHiG, *h1 = hLoG, *r0 = rHiG, *r1 = rLoG;
    unsigned* bp = bars + 256;
    float* yo = y1; int yld = 512;
    float *on = nullptr, *sn = st1;
    void* args[] = {&a0, &a1, &w0, &w1, &w2, &w3, &h0, &h1, &r0, &r1,
                    &bp, &yo, &yld, &on, &sn};
    hipLaunchCooperativeKernel((const void*)gru_scan_kernel<8>, dim3(256), dim3(256),
                               args, 0, stream);
  }
  {  // u2 input projections: [6400,512] x [512,1536]
    GemmSegs sg;
    sg.seg_end[0] = 1024; sg.seg_end[1] = 1536; sg.seg_end[2] = 1 << 30; sg.seg_end[3] = 1 << 30;
    sg.w[0] = WgU2; sg.w[1] = WcU2; sg.w[2] = nullptr; sg.w[3] = nullptr;
    sg.ldw[0] = 1024; sg.ldw[1] = 512; sg.ldw[2] = 0; sg.ldw[3] = 0;
    sg.bias[0] = bgU2; sg.bias[1] = bcU2; sg.bias[2] = nullptr; sg.bias[3] = nullptr;
    sg.c[0] = gxU2; sg.c[1] = gxU2; sg.c[2] = nullptr; sg.c[3] = nullptr;
    sg.col0[0] = 0; sg.col0[1] = 1024; sg.col0[2] = 0; sg.col0[3] = 0;
    gemm_f32_kernel<<<dim3(50, 12), 256, 0, stream>>>(y1, 512, 512, sg);
  }
  {  // u2 scan -> d_out (f32) + state2
    const float *a0 = gxU2, *a1 = nullptr;
    const unsigned short *w0 = wpU2Hi, *w1 = wpU2Lo, *w2 = nullptr, *w3 = nullptr;
    unsigned short *h0 = hHiG, *h1 = hLoG, *r0 = rHiG, *r1 = rLoG;
    unsigned* bp = bars + 512;
    float* yo = nullptr; int yld = 0;
    float *on = out, *sn = st2;
    void* args[] = {&a0, &a1, &w0, &w1, &w2, &w3, &h0, &h1, &r0, &r1,
                    &bp, &yo, &yld, &on, &sn};
    hipLaunchCooperativeKernel((const void*)gru_scan_kernel<8>, dim3(256), dim3(256),
                               args, 0, stream);
  }
}

// Round 6
// 2126.947 us; speedup vs baseline: 3.9234x; 1.0470x over previous
//
#include <hip/hip_runtime.h>
#include <hip/hip_bf16.h>

// GRU encoder: B=64, T=100, E=512, U=512.
// d_out = FLOAT32: output [B,T,U] then states [2,B,U]  (3,342,336 floats).
// Scan: sc1 LLC-coherent exchange + monotonic slot barriers + u-gate deferral
// (u MFMAs hide flag propagation), gx prefetch, post-flag y-writes.
// ws requirement ~131 MB.

#define TT 100

using f32x4 = __attribute__((ext_vector_type(4))) float;
using s16x8 = __attribute__((ext_vector_type(8))) short;

__device__ __forceinline__ unsigned short f2bfu(float x) {
  __hip_bfloat16 b = __float2bfloat16(x);
  unsigned short u;
  __builtin_memcpy(&u, &b, sizeof(u));
  return u;
}
__device__ __forceinline__ float bfu2f(unsigned short u) {
  __hip_bfloat16 b;
  __builtin_memcpy(&b, &u, sizeof(b));
  return __bfloat162float(b);
}
__device__ __forceinline__ float sigm(float x) {
  x = fminf(fmaxf(x, -30.f), 30.f);
  return 1.f / (1.f + __expf(-x));
}
__device__ __forceinline__ float tanh_fast(float x) {
  x = fminf(fmaxf(x, -15.f), 15.f);
  float e = __expf(-2.f * x);
  return (1.f - e) / (1.f + e);
}

// ---- LLC-coherent (bypass L1/L2) access helpers ----
__device__ __forceinline__ s16x8 sc1_load_b128(const void* p) {
  s16x8 v;
  asm volatile("global_load_dwordx4 %0, %1, off sc0 sc1" : "=v"(v) : "v"(p) : "memory");
  return v;
}
__device__ __forceinline__ void sc1_store_b16(void* p, unsigned v) {
  asm volatile("global_store_short %0, %1, off sc0 sc1" :: "v"(p), "v"(v) : "memory");
}
__device__ __forceinline__ void vm_drain() {
  asm volatile("s_waitcnt vmcnt(0)" ::: "memory");
}

// ---------------------------------------------------------------- embedding
__global__ __launch_bounds__(128) void embed_kernel(const int* __restrict__ x,
                                                    const float* __restrict__ emb,
                                                    float* __restrict__ xs) {
  const int row = blockIdx.x;            // row = t*64 + b  (time-major)
  const int t = row >> 6, b = row & 63;
  const int idx = x[b * TT + t];
  const f32x4* s = (const f32x4*)(emb + (size_t)idx * 512);
  f32x4* d = (f32x4*)(xs + (size_t)row * 512);
  d[threadIdx.x] = s[threadIdx.x];
}

// ------------------------------------------------- pack recurrent weights
// B-fragment layout for mfma_f32_16x16x32_bf16, split into bf16 hi/lo.
// [nt 0..95][kt 0..15][lane 0..63][elem 0..7]; nt 0..63 = gate cols,
// nt 64..95 = candidate cols. k = h-part rows (ein + k).
__global__ __launch_bounds__(256) void pack_w_kernel(const float* __restrict__ Wg,
                                                     const float* __restrict__ Wc,
                                                     int ldg, int ldc, int ein,
                                                     unsigned short* __restrict__ hi,
                                                     unsigned short* __restrict__ lo) {
  const int gg = blockIdx.x * 256 + threadIdx.x;
  if (gg >= 96 * 16 * 64) return;
  const int lane = gg & 63;
  const int pair = gg >> 6;
  const int kt = pair & 15;
  const int nt = pair >> 4;
  const int kg = lane >> 4;
  const int nl = lane & 15;
  const size_t off = (size_t)gg * 8;
  for (int i = 0; i < 8; ++i) {
    const int k = kt * 32 + kg * 8 + i;
    float v = (nt < 64) ? Wg[(size_t)(ein + k) * ldg + nt * 16 + nl]
                        : Wc[(size_t)(ein + k) * ldc + (nt - 64) * 16 + nl];
    unsigned short h = f2bfu(v);
    hi[off + i] = h;
    lo[off + i] = f2bfu(v - bfu2f(h));
  }
}

// ------------------------------------------------------- fp32 input-proj GEMM
struct GemmSegs {
  int seg_end[4];
  const float* w[4];
  int ldw[4];
  const float* bias[4];
  float* c[4];
  int col0[4];
};

__global__ __launch_bounds__(256) void gemm_f32_kernel(const float* __restrict__ A,
                                                       int lda, int K, GemmSegs segs) {
  __shared__ float As[16][132];
  __shared__ float Bs[16][132];
  const int tid = threadIdx.x;
  const int bm = blockIdx.x, bn = blockIdx.y;
  const int n0 = bn * 128;
  int s = 0;
  while (n0 >= segs.seg_end[s]) ++s;
  const int segst = s ? segs.seg_end[s - 1] : 0;
  const float* W = segs.w[s];
  const int ldw = segs.ldw[s];
  const float* bias = segs.bias[s] + (n0 - segst);
  float* C = segs.c[s];
  const int ccol = segs.col0[s] + (n0 - segst);
  const int wn0 = n0 - segst;

  const int alr = tid >> 1, alc = (tid & 1) * 8;
  const int blr = tid >> 4, blc = (tid & 15) * 8;
  const int tm = tid >> 4, tn = tid & 15;

  float acc[8][8] = {};
  const float* Arow = A + (size_t)(bm * 128 + alr) * lda + alc;
  const float* Wrow = W + (size_t)blr * ldw + wn0 + blc;

  for (int k0 = 0; k0 < K; k0 += 16) {
    f32x4 a0 = *(const f32x4*)(Arow + k0);
    f32x4 a1 = *(const f32x4*)(Arow + k0 + 4);
    f32x4 b0 = *(const f32x4*)(Wrow + (size_t)k0 * ldw);
    f32x4 b1 = *(const f32x4*)(Wrow + (size_t)k0 * ldw + 4);
#pragma unroll
    for (int i = 0; i < 4; ++i) {
      As[alc + i][alr] = a0[i];
      As[alc + 4 + i][alr] = a1[i];
    }
    *(f32x4*)&Bs[blr][blc] = b0;
    *(f32x4*)&Bs[blr][blc + 4] = b1;
    __syncthreads();
#pragma unroll
    for (int kk = 0; kk < 16; ++kk) {
      f32x4 xa = *(const f32x4*)&As[kk][tm * 4];
      f32x4 xb = *(const f32x4*)&As[kk][64 + tm * 4];
      f32x4 ya = *(const f32x4*)&Bs[kk][tn * 4];
      f32x4 yb = *(const f32x4*)&Bs[kk][64 + tn * 4];
#pragma unroll
      for (int i = 0; i < 4; ++i)
#pragma unroll
        for (int j = 0; j < 4; ++j) {
          acc[i][j] += xa[i] * ya[j];
          acc[i][j + 4] += xa[i] * yb[j];
          acc[i + 4][j] += xb[i] * ya[j];
          acc[i + 4][j + 4] += xb[i] * yb[j];
        }
    }
    __syncthreads();
  }
  float bv[8];
#pragma unroll
  for (int j = 0; j < 4; ++j) {
    bv[j] = bias[tn * 4 + j];
    bv[j + 4] = bias[64 + tn * 4 + j];
  }
#pragma unroll
  for (int i = 0; i < 8; ++i) {
    const int row = bm * 128 + ((i < 4) ? (tm * 4 + i) : (64 + tm * 4 + i - 4));
    float* cp = C + (size_t)row * 1536 + ccol;
    f32x4 v0, v1;
#pragma unroll
    for (int j = 0; j < 4; ++j) {
      v0[j] = acc[i][j] + bv[j];
      v1[j] = acc[i][j + 4] + bv[j + 4];
    }
    *(f32x4*)(cp + tn * 4) = v0;
    *(f32x4*)(cp + 64 + tn * 4) = v1;
  }
}

// ------------------------------------------------------------- GRU scan
// Grid 256 WGs = 8 groups x 32 WGs; WG owns hidden cols [wg*16, wg*16+16).
// Per step: G1r (r MFMAs) -> store r*h + flag -> G1u MFMAs + gx prefetch
// (hide flag latency) -> poll -> load r*h -> G2 (cand) -> store h' + flag
// -> y-writes (hide poll) -> poll -> load h'.
template <int NB>
__global__ __launch_bounds__(256, 1) void gru_scan_kernel(
    const float* __restrict__ gxF, const float* __restrict__ gxB,
    const unsigned short* __restrict__ wHiF, const unsigned short* __restrict__ wLoF,
    const unsigned short* __restrict__ wHiB, const unsigned short* __restrict__ wLoB,
    unsigned short* __restrict__ hHiG, unsigned short* __restrict__ hLoG,
    unsigned short* __restrict__ rHiG, unsigned short* __restrict__ rLoG,
    unsigned* __restrict__ slots,
    float* __restrict__ yout, int yld,
    float* __restrict__ outb,
    float* __restrict__ stout) {
  __shared__ unsigned short wHi_s[3 * 8192];   // 48KB: [r|u|c] tiles
  __shared__ unsigned short wLo_s[3 * 8192];   // 48KB
  __shared__ unsigned short hHi_s[8192];       // 16KB (h, then rh), swizzled
  __shared__ unsigned short hLo_s[8192];       // 16KB
  __shared__ float scr[4][16][17];             // r / cand partials
  __shared__ float scr2[4][16][17];            // u partials

  const int tid = threadIdx.x;
  const int lane = tid & 63;
  const int wv = tid >> 6;
  const int bid = blockIdx.x;
  const int g = bid & 7;
  const int wg = bid >> 3;
  const int hs = wg << 4;

  int dir = 0, b0;
  const float* gx;
  const unsigned short *wph, *wpl;
  if (NB == 16) {
    dir = g & 1;
    b0 = (g >> 1) << 4;
    gx = dir ? gxB : gxF;
    wph = dir ? wHiB : wHiF;
    wpl = dir ? wLoB : wLoF;
  } else {
    b0 = g * NB;
    gx = gxF;
    wph = wHiF;
    wpl = wLoF;
  }

  // stationary weight fragments -> LDS
  {
    const int nt0[3] = {wg, 32 + wg, 64 + wg};
    for (int c = 0; c < 3; ++c) {
      const unsigned short* sH = wph + (size_t)nt0[c] * 8192;
      const unsigned short* sL = wpl + (size_t)nt0[c] * 8192;
      unsigned short* dH = wHi_s + c * 8192;
      unsigned short* dL = wLo_s + c * 8192;
#pragma unroll
      for (int it = 0; it < 4; ++it) {
        const int o = (it * 256 + tid) * 8;
        *(s16x8*)(dH + o) = *(const s16x8*)(sH + o);
        *(s16x8*)(dL + o) = *(const s16x8*)(sL + o);
      }
    }
  }
  {  // h(0) = 0 (all 16 rows, so garbage rows stay finite for NB=8)
    s16x8 z = {0, 0, 0, 0, 0, 0, 0, 0};
#pragma unroll
    for (int it = 0; it < 4; ++it) {
      const int o = (it * 256 + tid) * 8;
      *(s16x8*)(hHi_s + o) = z;
      *(s16x8*)(hLo_s + o) = z;
    }
  }
  __syncthreads();

  unsigned* gslots = slots + g * 32;

  // MFMA lane constants
  const int fm = lane & 15;
  const int fkg = lane >> 4;
  const int arow = fm * 512;
  const int asw = (fm & 7) << 3;
  const int akof = fkg * 8;

  // uniform owner mapping: batch = tid>>4, col = tid&15
  const int ob = tid >> 4, oj = tid & 15;
  const bool own = (ob < NB);
  const int ui = ob * 512 + ((hs + oj) ^ ((ob & 7) << 3));

  const size_t tileo = (size_t)g * 8192;

  // tile MFMA: cidx 0=r, 1=u, 2=cand; each wave covers 4 kt
  auto mfma_tile = [&](int cidx, float dst[4][16][17]) {
    f32x4 acc0 = {0.f, 0.f, 0.f, 0.f}, acc1 = {0.f, 0.f, 0.f, 0.f};
    const int ktb = wv * 4;
#pragma unroll
    for (int q = 0; q < 4; ++q) {
      const int kt = ktb + q;
      const int ao = arow + ((kt * 32 + akof) ^ asw);
      s16x8 ah = *(const s16x8*)(hHi_s + ao);
      s16x8 al = *(const s16x8*)(hLo_s + ao);
      const int wo = ((cidx * 16 + kt) * 64 + lane) * 8;
      s16x8 bh = *(const s16x8*)(wHi_s + wo);
      s16x8 bl = *(const s16x8*)(wLo_s + wo);
      if (q & 1) {
        acc1 = __builtin_amdgcn_mfma_f32_16x16x32_bf16(ah, bh, acc1, 0, 0, 0);
        acc1 = __builtin_amdgcn_mfma_f32_16x16x32_bf16(ah, bl, acc1, 0, 0, 0);
        acc1 = __builtin_amdgcn_mfma_f32_16x16x32_bf16(al, bh, acc1, 0, 0, 0);
      } else {
        acc0 = __builtin_amdgcn_mfma_f32_16x16x32_bf16(ah, bh, acc0, 0, 0, 0);
        acc0 = __builtin_amdgcn_mfma_f32_16x16x32_bf16(ah, bl, acc0, 0, 0, 0);
        acc0 = __builtin_amdgcn_mfma_f32_16x16x32_bf16(al, bh, acc0, 0, 0, 0);
      }
    }
#pragma unroll
    for (int j = 0; j < 4; ++j) dst[wv][fkg * 4 + j][fm] = acc0[j] + acc1[j];
  };

  auto load_tile = [&](const unsigned short* SH, const unsigned short* SL) {
    s16x8 th[NB / 4], tl[NB / 4];
#pragma unroll
    for (int it = 0; it < NB / 4; ++it) {
      const int o = (it * 256 + tid) * 8;
      th[it] = sc1_load_b128(SH + tileo + o);
      tl[it] = sc1_load_b128(SL + tileo + o);
    }
    vm_drain();
#pragma unroll
    for (int it = 0; it < NB / 4; ++it) {
      const int o = (it * 256 + tid) * 8;
      *(s16x8*)(hHi_s + o) = th[it];
      *(s16x8*)(hLo_s + o) = tl[it];
    }
  };

  auto poll = [&](unsigned target) {
    if (tid < 32) {
      const unsigned* p = gslots + tid;
      unsigned v;
      do {
        asm volatile("global_load_dword %0, %1, off sc0 sc1\n\ts_waitcnt vmcnt(0)"
                     : "=v"(v) : "v"(p) : "memory");
      } while (!__all(v >= target));
    }
    __syncthreads();
  };

  // gx prefetch for step 0
  float gxr = 0.f, gxu = 0.f, gxc = 0.f;
  if (own) {
    const float* row = gx + ((size_t)(dir ? TT - 1 : 0) * 64 + b0 + ob) * 1536 + hs + oj;
    gxr = row[0]; gxu = row[512]; gxc = row[1024];
  }

  for (int t = 0; t < TT; ++t) {
    const int tg = dir ? (TT - 1 - t) : t;

    // ---- G1r: r-gate MFMAs ----
    mfma_tile(0, scr);
    __syncthreads();

    // ---- S1: sigmoid(r), store r*h (hi/lo) ----
    float hv = 0.f;
    if (own) {
      float rpre = scr[0][ob][oj] + scr[1][ob][oj] + scr[2][ob][oj] + scr[3][ob][oj] + gxr;
      float sg = sigm(rpre);
      hv = bfu2f(hHi_s[ui]) + bfu2f(hLo_s[ui]);
      float rh = sg * hv;
      unsigned short rhh = f2bfu(rh);
      sc1_store_b16(rHiG + tileo + ui, rhh);
      sc1_store_b16(rLoG + tileo + ui, f2bfu(rh - bfu2f(rhh)));
    }
    vm_drain();
    __syncthreads();
    if (tid == 0) {
      unsigned* p = gslots + wg;
      unsigned tv = 2 * t + 1;
      asm volatile("global_store_dword %0, %1, off sc0 sc1" :: "v"(p), "v"(tv) : "memory");
    }

    // ---- G1u: u-gate MFMAs (hide flag propagation) ----
    mfma_tile(1, scr2);

    // ---- prefetch next step's gx (issue only) ----
    float ngxr = 0.f, ngxu = 0.f, ngxc = 0.f;
    if (own && t + 1 < TT) {
      const int tgn = dir ? (TT - 2 - t) : (t + 1);
      const float* row = gx + ((size_t)tgn * 64 + b0 + ob) * 1536 + hs + oj;
      ngxr = row[0]; ngxu = row[512]; ngxc = row[1024];
    }

    poll(2 * t + 1);
    load_tile(rHiG, rLoG);    // r*h -> LDS (overwrites h)
    __syncthreads();

    // ---- G2: candidate MFMAs ----
    mfma_tile(2, scr);
    __syncthreads();

    // ---- S2: u from scr2, tanh, h update ----
    float hn = 0.f;
    if (own) {
      float upre = scr2[0][ob][oj] + scr2[1][ob][oj] + scr2[2][ob][oj] + scr2[3][ob][oj] + gxu;
      float uv = sigm(upre);
      float cpre = scr[0][ob][oj] + scr[1][ob][oj] + scr[2][ob][oj] + scr[3][ob][oj] + gxc;
      float cv = tanh_fast(cpre);
      hn = uv * hv + (1.f - uv) * cv;
    }

    if (t == TT - 1) {
      if (own) {
        if (yout) {
          const int ycol = (NB == 16) ? (dir * 512 + hs + oj) : (hs + oj);
          yout[((size_t)tg * 64 + (b0 + ob)) * yld + ycol] = hn;
        }
        if (outb) outb[((size_t)(b0 + ob) * TT + t) * 512 + hs + oj] = hn;
        if (stout) stout[(size_t)(b0 + ob) * 512 + hs + oj] = hn;
      }
      break;
    }

    if (own) {
      unsigned short hh = f2bfu(hn);
      sc1_store_b16(hHiG + tileo + ui, hh);
      sc1_store_b16(hLoG + tileo + ui, f2bfu(hn - bfu2f(hh)));
    }
    vm_drain();
    __syncthreads();
    if (tid == 0) {
      unsigned* p = gslots + wg;
      unsigned tv = 2 * t + 2;
      asm volatile("global_store_dword %0, %1, off sc0 sc1" :: "v"(p), "v"(tv) : "memory");
    }

    // ---- y-writes overlap the poll ----
    if (own) {
      if (yout) {
        const int ycol = (NB == 16) ? (dir * 512 + hs + oj) : (hs + oj);
        yout[((size_t)tg * 64 + (b0 + ob)) * yld + ycol] = hn;
      }
      if (outb) outb[((size_t)(b0 + ob) * TT + t) * 512 + hs + oj] = hn;
    }
    gxr = ngxr; gxu = ngxu; gxc = ngxc;

    poll(2 * t + 2);
    load_tile(hHiG, hLoG);    // h(t) -> LDS
    __syncthreads();
  }
}

// ---------------------------------------------------------------- launcher
extern "C" void kernel_launch(void* const* d_in, const int* in_sizes, int n_in,
                              void* d_out, int out_size, void* d_ws, size_t ws_size,
                              hipStream_t stream) {
  (void)in_sizes; (void)n_in; (void)out_size; (void)ws_size;
  const int* x = (const int*)d_in[0];
  const float* emb = (const float*)d_in[1];
  const float* WgFw = (const float*)d_in[2];
  const float* bgFw = (const float*)d_in[3];
  const float* WcFw = (const float*)d_in[4];
  const float* bcFw = (const float*)d_in[5];
  const float* WgBw = (const float*)d_in[6];
  const float* bgBw = (const float*)d_in[7];
  const float* WcBw = (const float*)d_in[8];
  const float* bcBw = (const float*)d_in[9];
  const float* WgU1 = (const float*)d_in[10];
  const float* bgU1 = (const float*)d_in[11];
  const float* WcU1 = (const float*)d_in[12];
  const float* bcU1 = (const float*)d_in[13];
  const float* WgU2 = (const float*)d_in[14];
  const float* bgU2 = (const float*)d_in[15];
  const float* WcU2 = (const float*)d_in[16];
  const float* bcU2 = (const float*)d_in[17];

  char* ws = (char*)d_ws;
  float* xs = (float*)(ws + 0);                      // 13,107,200 B
  float* bufA = (float*)(ws + 13107200);             // 39,321,600 B
  float* bufB = (float*)(ws + 52428800);             // 39,321,600 B
  float* ycat = (float*)(ws + 91750400);             // 26,214,400 B
  unsigned short* wp = (unsigned short*)(ws + 117964800);  // 12,582,912 B
  unsigned short* hb = (unsigned short*)(ws + 130547712);  // 524,288 B
  unsigned* bars = (unsigned*)(ws + 131072000);      // slot arrays
  float* y1 = xs;
  float* gxU1 = bufA;
  float* gxU2 = bufB;

  unsigned short* wpFwHi = wp + 0 * 786432;
  unsigned short* wpFwLo = wp + 1 * 786432;
  unsigned short* wpBwHi = wp + 2 * 786432;
  unsigned short* wpBwLo = wp + 3 * 786432;
  unsigned short* wpU1Hi = wp + 4 * 786432;
  unsigned short* wpU1Lo = wp + 5 * 786432;
  unsigned short* wpU2Hi = wp + 6 * 786432;
  unsigned short* wpU2Lo = wp + 7 * 786432;
  unsigned short* hHiG = hb;
  unsigned short* hLoG = hb + 65536;
  unsigned short* rHiG = hb + 131072;
  unsigned short* rLoG = hb + 196608;

  float* out = (float*)d_out;
  float* st1 = out + (size_t)64 * TT * 512;
  float* st2 = st1 + 64 * 512;

  hipMemsetAsync(bars, 0, 4096, stream);

  embed_kernel<<<6400, 128, 0, stream>>>(x, emb, xs);
  pack_w_kernel<<<384, 256, 0, stream>>>(WgFw, WcFw, 1024, 512, 512, wpFwHi, wpFwLo);
  pack_w_kernel<<<384, 256, 0, stream>>>(WgBw, WcBw, 1024, 512, 512, wpBwHi, wpBwLo);
  pack_w_kernel<<<384, 256, 0, stream>>>(WgU1, WcU1, 1024, 512, 1024, wpU1Hi, wpU1Lo);
  pack_w_kernel<<<384, 256, 0, stream>>>(WgU2, WcU2, 1024, 512, 512, wpU2Hi, wpU2Lo);

  {  // bidirectional input projections
    GemmSegs sg;
    sg.seg_end[0] = 1024; sg.seg_end[1] = 1536; sg.seg_end[2] = 2560; sg.seg_end[3] = 3072;
    sg.w[0] = WgFw; sg.w[1] = WcFw; sg.w[2] = WgBw; sg.w[3] = WcBw;
    sg.ldw[0] = 1024; sg.ldw[1] = 512; sg.ldw[2] = 1024; sg.ldw[3] = 512;
    sg.bias[0] = bgFw; sg.bias[1] = bcFw; sg.bias[2] = bgBw; sg.bias[3] = bcBw;
    sg.c[0] = bufA; sg.c[1] = bufA; sg.c[2] = bufB; sg.c[3] = bufB;
    sg.col0[0] = 0; sg.col0[1] = 1024; sg.col0[2] = 0; sg.col0[3] = 1024;
    gemm_f32_kernel<<<dim3(50, 24), 256, 0, stream>>>(xs, 512, 512, sg);
  }
  {  // bidirectional scan
    const float *a0 = bufA, *a1 = bufB;
    const unsigned short *w0 = wpFwHi, *w1 = wpFwLo, *w2 = wpBwHi, *w3 = wpBwLo;
    unsigned short *h0 = hHiG, *h1 = hLoG, *r0 = rHiG, *r1 = rLoG;
    unsigned* bp = bars;
    float* yo = ycat; int yld = 1024;
    float *on = nullptr, *sn = nullptr;
    void* args[] = {&a0, &a1, &w0, &w1, &w2, &w3, &h0, &h1, &r0, &r1,
                    &bp, &yo, &yld, &on, &sn};
    hipLaunchCooperativeKernel((const void*)gru_scan_kernel<16>, dim3(256), dim3(256),
                               args, 0, stream);
  }
  {  // u1 input projections
    GemmSegs sg;
    sg.seg_end[0] = 1024; sg.seg_end[1] = 1536; sg.seg_end[2] = 1 << 30; sg.seg_end[3] = 1 << 30;
    sg.w[0] = WgU1; sg.w[1] = WcU1; sg.w[2] = nullptr; sg.w[3] = nullptr;
    sg.ldw[0] = 1024; sg.ldw[1] = 512; sg.ldw[2] = 0; sg.ldw[3] = 0;
    sg.bias[0] = bgU1; sg.bias[1] = bcU1; sg.bias[2] = nullptr; sg.bias[3] = nullptr;
    sg.c[0] = gxU1; sg.c[1] = gxU1; sg.c[2] = nullptr; sg.c[3] = nullptr;
    sg.col0[0] = 0; sg.col0[1] = 1024; sg.col0[2] = 0; sg.col0[3] = 0;
    gemm_f32_kernel<<<dim3(50, 12), 256, 0, stream>>>(ycat, 1024, 1024, sg);
  }
  {  // u1 scan
    const float *a0 = gxU1, *a1 = nullptr;
    const unsigned short *w0 = wpU1Hi, *w1 = wpU1Lo, *w2 = nullptr, *w3 = nullptr;
    unsigned short *h0 = hHiG, *h1 = hLoG, *r0 = rHiG, *r1 = rLoG;
    unsigned* bp = bars + 256;
    float* yo = y1; int yld = 512;
    float *on = nullptr, *sn = st1;
    void* args[] = {&a0, &a1, &w0, &w1, &w2, &w3, &h0, &h1, &r0, &r1,
                    &bp, &yo, &yld, &on, &sn};
    hipLaunchCooperativeKernel((const void*)gru_scan_kernel<8>, dim3(256), dim3(256),
                               args, 0, stream);
  }
  {  // u2 input projections
    GemmSegs sg;
    sg.seg_end[0] = 1024; sg.seg_end[1] = 1536; sg.seg_end[2] = 1 << 30; sg.seg_end[3] = 1 << 30;
    sg.w[0] = WgU2; sg.w[1] = WcU2; sg.w[2] = nullptr; sg.w[3] = nullptr;
    sg.ldw[0] = 1024; sg.ldw[1] = 512; sg.ldw[2] = 0; sg.ldw[3] = 0;
    sg.bias[0] = bgU2; sg.bias[1] = bcU2; sg.bias[2] = nullptr; sg.bias[3] = nullptr;
    sg.c[0] = gxU2; sg.c[1] = gxU2; sg.c[2] = nullptr; sg.c[3] = nullptr;
    sg.col0[0] = 0; sg.col0[1] = 1024; sg.col0[2] = 0; sg.col0[3] = 0;
    gemm_f32_kernel<<<dim3(50, 12), 256, 0, stream>>>(y1, 512, 512, sg);
  }
  {  // u2 scan -> d_out (f32) + state2
    const float *a0 = gxU2, *a1 = nullptr;
    const unsigned short *w0 = wpU2Hi, *w1 = wpU2Lo, *w2 = nullptr, *w3 = nullptr;
    unsigned short *h0 = hHiG, *h1 = hLoG, *r0 = rHiG, *r1 = rLoG;
    unsigned* bp = bars + 512;
    float* yo = nullptr; int yld = 0;
    float *on = out, *sn = st2;
    void* args[] = {&a0, &a1, &w0, &w1, &w2, &w3, &h0, &h1, &r0, &r1,
                    &bp, &yo, &yld, &on, &sn};
    hipLaunchCooperativeKernel((const void*)gru_scan_kernel<8>, dim3(256), dim3(256),
                               args, 0, stream);
  }
}